// Round 3
// baseline (951.607 us; speedup 1.0000x reference)
//
#include <hip/hip_runtime.h>

// Performer linear attention: n=2, l=2048, h=8, e=64, m=2048
// Dtype (fp32 vs bf16) detected at runtime from the projection buffer.
// ws (floats): flag[64] | c_k[32768] | c_q[32768] | ksum[16*2048] | kvf[16*2048*64]  ~8.8 MB

#define LL 2048
#define HH 8
#define MM 2048

#define NORMC 0.35355339059327373f   // 64^-0.25
#define RATIO 0.022097086912079608f  // 2048^-0.5
#define KEPS 1e-4f
#define EPSD 1e-6f

__device__ __forceinline__ float bf2f(unsigned short u) {
    union { unsigned int ui; float f; } v; v.ui = ((unsigned int)u) << 16; return v.f;
}
__device__ __forceinline__ unsigned short f2bf(float f) {
    union { float f; unsigned int u; } v; v.f = f;
    unsigned int r = v.u + 0x7fffu + ((v.u >> 16) & 1u);
    return (unsigned short)(r >> 16);
}

template <bool BF16>
__device__ __forceinline__ float4 ld4(const void* p, size_t elem_off) {
    if (BF16) {
        ushort4 u = *(const ushort4*)((const unsigned short*)p + elem_off);
        return make_float4(bf2f(u.x), bf2f(u.y), bf2f(u.z), bf2f(u.w));
    } else {
        return *(const float4*)((const float*)p + elem_off);
    }
}

// Stage 64 rows x 64 cols, TRANSPOSED into D[col][row], scaled.
template <bool BF16>
__device__ __forceinline__ void stage_T(const void* X, size_t base, size_t stride,
                                        float scale, float D[64][68], int t) {
    const int tx = t & 15, ty = t >> 4;
    #pragma unroll
    for (int j = 0; j < 4; ++j) {
        const int r = ty + 16 * j;
        float4 v = ld4<BF16>(X, base + (size_t)r * stride + tx * 4);
        D[tx * 4 + 0][r] = v.x * scale;
        D[tx * 4 + 1][r] = v.y * scale;
        D[tx * 4 + 2][r] = v.z * scale;
        D[tx * 4 + 3][r] = v.w * scale;
    }
}

// Stage 64 rows x 64 cols, natural layout D[row][col].
template <bool BF16>
__device__ __forceinline__ void stage_N(const void* X, size_t base, size_t stride,
                                        float D[64][68], int t) {
    const int tx = t & 15, ty = t >> 4;
    #pragma unroll
    for (int j = 0; j < 4; ++j) {
        const int r = ty + 16 * j;
        float4 v = ld4<BF16>(X, base + (size_t)r * stride + tx * 4);
        *(float4*)&D[r][tx * 4] = v;
    }
}

// acc[i][j] += sum_k A[k][rt*4+i] * B[k][ct*4+j]
__device__ __forceinline__ void gemm_tile(const float A[64][68], const float B[64][68],
                                          int rt, int ct, float acc[4][4]) {
    #pragma unroll 4
    for (int k = 0; k < 64; ++k) {
        const float4 x = *(const float4*)&A[k][rt * 4];
        const float4 p = *(const float4*)&B[k][ct * 4];
        const float xa[4] = {x.x, x.y, x.z, x.w};
        const float pa[4] = {p.x, p.y, p.z, p.w};
        #pragma unroll
        for (int i = 0; i < 4; ++i)
            #pragma unroll
            for (int j = 0; j < 4; ++j)
                acc[i][j] = fmaf(xa[i], pa[j], acc[i][j]);
    }
}

// ---------------- dtype detection ----------------
__global__ void LinearAttention_15985868276494_detect(const unsigned short* __restrict__ P,
                                                      float* __restrict__ flag) {
    if (threadIdx.x == 0) {
        int sane = 1;
        #pragma unroll
        for (int i = 0; i < 16; ++i) {
            const unsigned e = (P[2 * i] >> 7) & 0xFF;
            if (e < 101 || e > 141) sane = 0;  // |x| outside [1e-8, 1e4] -> not bf16 data
        }
        *flag = sane ? 1.0f : 0.0f;
    }
}

// ---------------- stats: c[row] = rowmax(x.P^T) + 0.5*|x*normc|^2 ----------------
template <bool BF16>
__device__ void stats_impl(const void* X, const void* P, float* cout,
                           float XT[64][68], float PT[64][68], float red[16][64]) {
    const int t = threadIdx.x;
    const int row_base = blockIdx.x * 64;
    stage_T<BF16>(X, (size_t)row_base * 64, 64, NORMC, XT, t);

    const int rt = t & 15, ct = t >> 4;
    float rmax[4] = {-1e30f, -1e30f, -1e30f, -1e30f};
    for (int mt = 0; mt < 32; ++mt) {
        __syncthreads();
        stage_T<BF16>(P, (size_t)(mt * 64) * 64, 64, 1.0f, PT, t);
        __syncthreads();
        float acc[4][4] = {};
        gemm_tile(XT, PT, rt, ct, acc);
        #pragma unroll
        for (int i = 0; i < 4; ++i)
            rmax[i] = fmaxf(rmax[i],
                            fmaxf(fmaxf(acc[i][0], acc[i][1]), fmaxf(acc[i][2], acc[i][3])));
    }
    #pragma unroll
    for (int i = 0; i < 4; ++i) red[ct][rt * 4 + i] = rmax[i];
    __syncthreads();
    if (t < 64) {
        float mx = red[0][t];
        #pragma unroll
        for (int j = 1; j < 16; ++j) mx = fmaxf(mx, red[j][t]);
        float s2 = 0.f;
        #pragma unroll 8
        for (int k = 0; k < 64; ++k) { const float x = XT[k][t]; s2 = fmaf(x, x, s2); }
        cout[row_base + t] = mx + 0.5f * s2;
    }
}

__global__ __launch_bounds__(256) void LinearAttention_15985868276494_stats(
        const void* X, const void* P, const float* flag, float* cout) {
    __shared__ float XT[64][68];
    __shared__ float PT[64][68];
    __shared__ float red[16][64];
    if (*flag != 0.f) stats_impl<true>(X, P, cout, XT, PT, red);
    else stats_impl<false>(X, P, cout, XT, PT, red);
}

// ---------------- kv: kvf[nh][m][e], ksum[nh][m] ----------------
template <bool BF16>
__device__ void kv_impl(const void* K, const void* V, const void* P, const float* ck,
                        float* kvf, float* ksum,
                        float XTF[64][68], float PT[64][68], float VS[64][68]) {
    const int t = threadIdx.x;
    const int mt = blockIdx.x;   // 0..31
    const int nh = blockIdx.y;   // 0..15
    const int n = nh >> 3, h = nh & 7;
    const size_t base = (size_t)n * (LL * HH * 64) + (size_t)h * 64;

    stage_T<BF16>(P, (size_t)(mt * 64) * 64, 64, 1.0f, PT, t);

    const int rt = t & 15, ct = t >> 4;
    float akv[4][4] = {};
    float ks[4] = {};

    for (int st = 0; st < 32; ++st) {
        __syncthreads();  // B1: prev iter gemm2 reads done (and pre-loop PT at st=0)
        stage_T<BF16>(K, base + (size_t)(st * 64) * (HH * 64), HH * 64, NORMC, XTF, t);
        stage_N<BF16>(V, base + (size_t)(st * 64) * (HH * 64), HH * 64, VS, t);
        __syncthreads();  // B2
        float acc[4][4] = {};
        gemm_tile(XTF, PT, rt, ct, acc);
        __syncthreads();  // B3: all XT reads done before F overwrites the same LDS
        #pragma unroll
        for (int i = 0; i < 4; ++i) {
            const int s = st * 64 + rt * 4 + i;
            const float c = ck[(size_t)(n * LL + s) * HH + h];
            float4 f;
            f.x = RATIO * (__expf(fminf(acc[i][0] - c, 0.f)) + KEPS);
            f.y = RATIO * (__expf(fminf(acc[i][1] - c, 0.f)) + KEPS);
            f.z = RATIO * (__expf(fminf(acc[i][2] - c, 0.f)) + KEPS);
            f.w = RATIO * (__expf(fminf(acc[i][3] - c, 0.f)) + KEPS);
            *(float4*)&XTF[rt * 4 + i][ct * 4] = f;   // F[s_local][m_local]
        }
        __syncthreads();  // B4
        #pragma unroll 4
        for (int s = 0; s < 64; ++s) {
            const float4 f4 = *(const float4*)&XTF[s][rt * 4];
            const float4 v4 = *(const float4*)&VS[s][ct * 4];
            const float fa[4] = {f4.x, f4.y, f4.z, f4.w};
            const float va[4] = {v4.x, v4.y, v4.z, v4.w};
            #pragma unroll
            for (int jm = 0; jm < 4; ++jm)
                #pragma unroll
                for (int ie = 0; ie < 4; ++ie)
                    akv[jm][ie] = fmaf(fa[jm], va[ie], akv[jm][ie]);
            if (ct == 0) {
                #pragma unroll
                for (int jm = 0; jm < 4; ++jm) ks[jm] += fa[jm];
            }
        }
    }
    #pragma unroll
    for (int jm = 0; jm < 4; ++jm) {
        const int m = mt * 64 + rt * 4 + jm;
        *(float4*)&kvf[((size_t)nh * MM + m) * 64 + ct * 4] =
            make_float4(akv[jm][0], akv[jm][1], akv[jm][2], akv[jm][3]);
    }
    if (ct == 0) {
        #pragma unroll
        for (int jm = 0; jm < 4; ++jm)
            ksum[(size_t)nh * MM + mt * 64 + rt * 4 + jm] = ks[jm];
    }
}

__global__ __launch_bounds__(256) void LinearAttention_15985868276494_kv(
        const void* K, const void* V, const void* P, const float* flag,
        const float* ck, float* kvf, float* ksum) {
    __shared__ float XTF[64][68];
    __shared__ float PT[64][68];
    __shared__ float VS[64][68];
    if (*flag != 0.f) kv_impl<true>(K, V, P, ck, kvf, ksum, XTF, PT, VS);
    else kv_impl<false>(K, V, P, ck, kvf, ksum, XTF, PT, VS);
}

// ---------------- out ----------------
template <bool BF16>
__device__ void out_impl(const void* Q, const void* P, const float* cq,
                         const float* kvf, const float* ksum, void* out,
                         float XT[64][68], float PTQF[64][68], float KV[64][68],
                         float* KS, float* Z) {
    const int t = threadIdx.x;
    const int lb = blockIdx.x;   // 0..31
    const int nh = blockIdx.y;   // 0..15
    const int n = nh >> 3, h = nh & 7;
    const size_t base = (size_t)n * (LL * HH * 64) + (size_t)h * 64;

    stage_T<BF16>(Q, base + (size_t)(lb * 64) * (HH * 64), HH * 64, NORMC, XT, t);

    const int rt = t & 15, ct = t >> 4;
    float aout[4][4] = {};
    float dsum[4] = {};
    float c4[4];
    #pragma unroll
    for (int i = 0; i < 4; ++i)
        c4[i] = cq[(size_t)(n * LL + lb * 64 + rt * 4 + i) * HH + h];

    for (int mt = 0; mt < 32; ++mt) {
        __syncthreads();  // B1: prev gemm2 reads of PTQF/KV/KS done
        stage_T<BF16>(P, (size_t)(mt * 64) * 64, 64, 1.0f, PTQF, t);
        {
            const int tx = t & 15, ty = t >> 4;
            #pragma unroll
            for (int j = 0; j < 4; ++j) {
                const int mr = ty + 16 * j;
                *(float4*)&KV[mr][tx * 4] =
                    *(const float4*)&kvf[((size_t)nh * MM + mt * 64 + mr) * 64 + tx * 4];
            }
            if (t < 64) KS[t] = ksum[(size_t)nh * MM + mt * 64 + t];
        }
        __syncthreads();  // B2 (covers pre-loop XT at mt=0)
        float acc[4][4] = {};
        gemm_tile(XT, PTQF, rt, ct, acc);
        __syncthreads();  // B3: PT reads done before QF overwrites the same LDS
        #pragma unroll
        for (int j = 0; j < 4; ++j) {
            float4 f;
            f.x = RATIO * (__expf(fminf(acc[0][j] - c4[0], 0.f)) + KEPS);
            f.y = RATIO * (__expf(fminf(acc[1][j] - c4[1], 0.f)) + KEPS);
            f.z = RATIO * (__expf(fminf(acc[2][j] - c4[2], 0.f)) + KEPS);
            f.w = RATIO * (__expf(fminf(acc[3][j] - c4[3], 0.f)) + KEPS);
            *(float4*)&PTQF[ct * 4 + j][rt * 4] = f;   // QF[m_local][l_local]
        }
        __syncthreads();  // B4
        #pragma unroll 4
        for (int m = 0; m < 64; ++m) {
            const float4 q4 = *(const float4*)&PTQF[m][rt * 4];
            const float4 k4 = *(const float4*)&KV[m][ct * 4];
            const float qa[4] = {q4.x, q4.y, q4.z, q4.w};
            const float ka[4] = {k4.x, k4.y, k4.z, k4.w};
            #pragma unroll
            for (int il = 0; il < 4; ++il)
                #pragma unroll
                for (int ie = 0; ie < 4; ++ie)
                    aout[il][ie] = fmaf(qa[il], ka[ie], aout[il][ie]);
            if (ct == 0) {
                const float ksm = KS[m];
                #pragma unroll
                for (int il = 0; il < 4; ++il) dsum[il] = fmaf(qa[il], ksm, dsum[il]);
            }
        }
    }
    if (ct == 0) {
        #pragma unroll
        for (int il = 0; il < 4; ++il) Z[rt * 4 + il] = 1.0f / (dsum[il] + EPSD);
    }
    __syncthreads();
    #pragma unroll
    for (int il = 0; il < 4; ++il) {
        const int l = lb * 64 + rt * 4 + il;
        const float z = Z[rt * 4 + il];
        const size_t idx = ((size_t)(n * LL + l) * HH + h) * 64 + ct * 4;
        if (BF16) {
            ushort4 o;
            o.x = f2bf(aout[il][0] * z);
            o.y = f2bf(aout[il][1] * z);
            o.z = f2bf(aout[il][2] * z);
            o.w = f2bf(aout[il][3] * z);
            *(ushort4*)((unsigned short*)out + idx) = o;
        } else {
            *(float4*)((float*)out + idx) =
                make_float4(aout[il][0] * z, aout[il][1] * z, aout[il][2] * z, aout[il][3] * z);
        }
    }
}

__global__ __launch_bounds__(256) void LinearAttention_15985868276494_out(
        const void* Q, const void* P, const float* flag, const float* cq,
        const float* kvf, const float* ksum, void* out) {
    __shared__ float XT[64][68];
    __shared__ float PTQF[64][68];
    __shared__ float KV[64][68];
    __shared__ float KS[64];
    __shared__ float Z[64];
    if (*flag != 0.f) out_impl<true>(Q, P, cq, kvf, ksum, out, XT, PTQF, KV, KS, Z);
    else out_impl<false>(Q, P, cq, kvf, ksum, out, XT, PTQF, KV, KS, Z);
}

extern "C" void kernel_launch(void* const* d_in, const int* in_sizes, int n_in,
                              void* d_out, int out_size, void* d_ws, size_t ws_size,
                              hipStream_t stream) {
    const void* Q = d_in[0];
    const void* K = d_in[1];
    const void* V = d_in[2];
    const void* P = d_in[3];

    float* W = (float*)d_ws;
    float* flag = W;                    // [64]
    float* c_k = W + 64;                // [32768]
    float* c_q = c_k + 32768;           // [32768]
    float* ksumW = c_q + 32768;         // [32768]
    float* kvfW = ksumW + 32768;        // [16*2048*64]

    LinearAttention_15985868276494_detect<<<1, 64, 0, stream>>>(
        (const unsigned short*)P, flag);
    LinearAttention_15985868276494_stats<<<512, 256, 0, stream>>>(K, P, flag, c_k);
    LinearAttention_15985868276494_stats<<<512, 256, 0, stream>>>(Q, P, flag, c_q);
    LinearAttention_15985868276494_kv<<<dim3(32, 16), 256, 0, stream>>>(
        K, V, P, flag, c_k, kvfW, ksumW);
    LinearAttention_15985868276494_out<<<dim3(32, 16), 256, 0, stream>>>(
        Q, P, flag, c_q, kvfW, ksumW, d_out);
}

// Round 4
// 248.886 us; speedup vs baseline: 3.8235x; 3.8235x over previous
//
#include <hip/hip_runtime.h>

// Performer linear attention, MFMA bf16 version.
// n=2, l=2048, h=8, e=64, m=2048. Dtype runtime-detected (bf16 confirmed by R3 absmax).
// ws: flag f32[16] | c_k f32[16][2048] | c_q f32[16][2048] | ksum f32[16][2048]
//     | kvT bf16[16][64][2048]   (~4.4 MB)

#define LL 2048
#define HH 8
#define MM 2048
#define ROWSTR 512  // h-strided row stride of Q/K/V rows: HH*64

#define NORMC 0.35355339059327373f   // 64^-0.25
#define RATIO 0.022097086912079608f  // 2048^-0.5
#define KEPS 1e-4f
#define REPS (RATIO * KEPS)
#define EPSD 1e-6f

typedef __attribute__((ext_vector_type(8))) short short8;
typedef __attribute__((ext_vector_type(4))) float f32x4;

#define MFMA(a, b, c) __builtin_amdgcn_mfma_f32_16x16x32_bf16((a), (b), (c), 0, 0, 0)

__device__ __forceinline__ unsigned short f2bf(float f) {  // RNE
    union { float f; unsigned int u; } v; v.f = f;
    unsigned int r = v.u + 0x7fffu + ((v.u >> 16) & 1u);
    return (unsigned short)(r >> 16);
}
__device__ __forceinline__ float bf2f(unsigned short u) {
    union { unsigned int ui; float f; } v; v.ui = ((unsigned int)u) << 16; return v.f;
}
// pack two f32 -> two bf16 (truncation) in one v_perm
__device__ __forceinline__ unsigned int pk2(float lo, float hi) {
    return __builtin_amdgcn_perm(__float_as_uint(hi), __float_as_uint(lo), 0x07060302u);
}

// Stage a 64x64 tile (row-major, rstride elems) into LDS bf16 [64][72].
template <bool BF16>
__device__ __forceinline__ void stage_tile(const void* src, size_t base, size_t rstride,
                                           unsigned short D[64][72], int t) {
    const int row = t >> 2, c16 = (t & 3) * 16;
    if (BF16) {
        const unsigned short* p = (const unsigned short*)src + base + (size_t)row * rstride + c16;
        uint4 u0 = *(const uint4*)p;
        uint4 u1 = *(const uint4*)(p + 8);
        *(uint4*)&D[row][c16] = u0;
        *(uint4*)&D[row][c16 + 8] = u1;
    } else {
        const float* p = (const float*)src + base + (size_t)row * rstride + c16;
        float4 f0 = ((const float4*)p)[0], f1 = ((const float4*)p)[1];
        float4 f2 = ((const float4*)p)[2], f3 = ((const float4*)p)[3];
        uint4 a, b;
        a.x = pk2(f0.x, f0.y); a.y = pk2(f0.z, f0.w);
        a.z = pk2(f1.x, f1.y); a.w = pk2(f1.z, f1.w);
        b.x = pk2(f2.x, f2.y); b.y = pk2(f2.z, f2.w);
        b.z = pk2(f3.x, f3.y); b.w = pk2(f3.z, f3.w);
        *(uint4*)&D[row][c16] = a;
        *(uint4*)&D[row][c16 + 8] = b;
    }
}

// Stage V tile transposed: VT[e][s] from V rows (stride ROWSTR).
template <bool BF16>
__device__ __forceinline__ void stage_VT(const void* V, size_t base,
                                         unsigned short VT[64][72], int t) {
    const int s = t >> 2, e0 = (t & 3) * 16;
    if (BF16) {
        const unsigned short* p = (const unsigned short*)V + base + (size_t)s * ROWSTR + e0;
        uint4 u0 = *(const uint4*)p;
        uint4 u1 = *(const uint4*)(p + 8);
        unsigned int u[8] = {u0.x, u0.y, u0.z, u0.w, u1.x, u1.y, u1.z, u1.w};
        #pragma unroll
        for (int i = 0; i < 8; ++i) {
            VT[e0 + 2 * i][s] = (unsigned short)(u[i] & 0xFFFFu);
            VT[e0 + 2 * i + 1][s] = (unsigned short)(u[i] >> 16);
        }
    } else {
        const float* p = (const float*)V + base + (size_t)s * ROWSTR + e0;
        #pragma unroll
        for (int i = 0; i < 16; ++i)
            VT[e0 + i][s] = (unsigned short)(__float_as_uint(p[i]) >> 16);
    }
}

// ---------------- dtype detection ----------------
__global__ void LinearAttention_15985868276494_detect(const unsigned short* __restrict__ P,
                                                      float* __restrict__ flag) {
    if (threadIdx.x == 0) {
        int sane = 1;
        #pragma unroll
        for (int i = 0; i < 16; ++i) {
            const unsigned e = (P[2 * i] >> 7) & 0xFF;
            if (e < 101 || e > 141) sane = 0;
        }
        *flag = sane ? 1.0f : 0.0f;
    }
}

// ---------------- stats: c[nh][l] = normc*rowmax(X.P^T) + 0.5*normc^2*|x|^2 ----------------
template <bool BF16>
__device__ void stats_impl(const void* X, const void* P, float* cws,
                           unsigned short Xs[64][72], unsigned short Ps[64][72],
                           float* diag_s) {
    const int t = threadIdx.x;
    const int w = t >> 6, ln = t & 15, quad = (t >> 4) & 3;
    const int row_base = blockIdx.x * 64;

    stage_tile<BF16>(X, (size_t)row_base * 64, 64, Xs, t);
    __syncthreads();
    if (t < 64) {
        float s2 = 0.f;
        #pragma unroll
        for (int c = 0; c < 64; c += 8) {
            uint4 u = *(const uint4*)&Xs[t][c];
            const unsigned int ua[4] = {u.x, u.y, u.z, u.w};
            #pragma unroll
            for (int i = 0; i < 4; ++i) {
                float lo = bf2f((unsigned short)(ua[i] & 0xFFFF));
                float hi = bf2f((unsigned short)(ua[i] >> 16));
                s2 = fmaf(lo, lo, s2); s2 = fmaf(hi, hi, s2);
            }
        }
        diag_s[t] = s2;
    }
    // hoist B-frags (X rows of this wave's strip)
    const short8 xb0 = *(const short8*)&Xs[16 * w + ln][quad * 8];
    const short8 xb1 = *(const short8*)&Xs[16 * w + ln][32 + quad * 8];

    float rmax = -3.0e38f;
    for (int mt = 0; mt < 32; ++mt) {
        __syncthreads();
        stage_tile<BF16>(P, (size_t)(mt * 64) * 64, 64, Ps, t);
        __syncthreads();
        #pragma unroll
        for (int ms = 0; ms < 4; ++ms) {
            f32x4 acc = {0.f, 0.f, 0.f, 0.f};
            acc = MFMA(*(const short8*)&Ps[16 * ms + ln][quad * 8], xb0, acc);
            acc = MFMA(*(const short8*)&Ps[16 * ms + ln][32 + quad * 8], xb1, acc);
            rmax = fmaxf(rmax, fmaxf(fmaxf(acc[0], acc[1]), fmaxf(acc[2], acc[3])));
        }
    }
    rmax = fmaxf(rmax, __shfl_xor(rmax, 16));
    rmax = fmaxf(rmax, __shfl_xor(rmax, 32));
    __syncthreads();
    if ((t & 63) < 16) {
        const int row = 16 * w + ln;
        const int rg = row_base + row;
        const int n = rg >> 14, l = (rg >> 3) & 2047, h = rg & 7;
        const float c = NORMC * rmax + (0.5f * NORMC * NORMC) * diag_s[row];
        cws[(size_t)((n << 3) | h) * LL + l] = c;
    }
}

__global__ __launch_bounds__(256) void LinearAttention_15985868276494_stats(
        const void* X, const void* P, const float* flag, float* cws) {
    __shared__ unsigned short Xs[64][72];
    __shared__ unsigned short Ps[64][72];
    __shared__ float diag_s[64];
    if (*flag != 0.f) stats_impl<true>(X, P, cws, Xs, Ps, diag_s);
    else stats_impl<false>(X, P, cws, Xs, Ps, diag_s);
}

// ---------------- kv: kvT[nh][e][m] (bf16), ksum[nh][m] (f32) ----------------
template <bool BF16>
__device__ void kv_impl(const void* K, const void* V, const void* P, const float* cws,
                        unsigned short* kvT, float* ksum,
                        unsigned short Ks[64][72], unsigned short Ps[64][72],
                        unsigned short VT[64][72], unsigned short FT[64][72], float* cks) {
    const int t = threadIdx.x;
    const int w = t >> 6, ln = t & 15, quad = (t >> 4) & 3;
    const int mt = blockIdx.x, nh = blockIdx.y;
    const int n = nh >> 3, h = nh & 7;
    const size_t xbase = (size_t)n * (LL * ROWSTR) + (size_t)h * 64;

    stage_tile<BF16>(P, (size_t)(mt * 64) * 64, 64, Ps, t);

    f32x4 akv[4] = {{0.f, 0.f, 0.f, 0.f}, {0.f, 0.f, 0.f, 0.f},
                    {0.f, 0.f, 0.f, 0.f}, {0.f, 0.f, 0.f, 0.f}};
    f32x4 aks = {0.f, 0.f, 0.f, 0.f};
    const short8 ones = {0x3F80, 0x3F80, 0x3F80, 0x3F80, 0x3F80, 0x3F80, 0x3F80, 0x3F80};

    for (int st = 0; st < 32; ++st) {
        __syncthreads();  // B1: prev MFMA2 reads (VT/FT) + (st==0) Ps staged
        stage_tile<BF16>(K, xbase + (size_t)(st * 64) * ROWSTR, ROWSTR, Ks, t);
        stage_VT<BF16>(V, xbase + (size_t)(st * 64) * ROWSTR, VT, t);
        if (t < 64) cks[t] = cws[(size_t)nh * LL + st * 64 + t];
        __syncthreads();  // B2
        const short8 pb0 = *(const short8*)&Ps[16 * w + ln][quad * 8];
        const short8 pb1 = *(const short8*)&Ps[16 * w + ln][32 + quad * 8];
        #pragma unroll
        for (int ss = 0; ss < 4; ++ss) {
            f32x4 acc = {0.f, 0.f, 0.f, 0.f};
            acc = MFMA(*(const short8*)&Ks[16 * ss + ln][quad * 8], pb0, acc);
            acc = MFMA(*(const short8*)&Ks[16 * ss + ln][32 + quad * 8], pb1, acc);
            const float4 c4 = *(const float4*)&cks[16 * ss + 4 * quad];
            const float ca[4] = {c4.x, c4.y, c4.z, c4.w};
            float f[4];
            #pragma unroll
            for (int i = 0; i < 4; ++i) {
                const float arg = fminf(fmaf(acc[i], NORMC, -ca[i]), 0.f);
                f[i] = fmaf(__expf(arg), RATIO, REPS);
            }
            uint2 o; o.x = pk2(f[0], f[1]); o.y = pk2(f[2], f[3]);
            *(uint2*)&FT[16 * w + ln][16 * ss + 4 * quad] = o;
        }
        __syncthreads();  // B3
        #pragma unroll
        for (int k = 0; k < 2; ++k) {
            const short8 af = *(const short8*)&FT[16 * w + ln][32 * k + quad * 8];
            aks = MFMA(af, ones, aks);
            #pragma unroll
            for (int es = 0; es < 4; ++es)
                akv[es] = MFMA(af, *(const short8*)&VT[16 * es + ln][32 * k + quad * 8], akv[es]);
        }
    }
    // store kvT[nh][e][m]: lane cols e=16es+ln, rows m = mt*64 + 16w + 4*quad + reg
    #pragma unroll
    for (int es = 0; es < 4; ++es) {
        uint2 o;
        o.x = (unsigned)f2bf(akv[es][0]) | ((unsigned)f2bf(akv[es][1]) << 16);
        o.y = (unsigned)f2bf(akv[es][2]) | ((unsigned)f2bf(akv[es][3]) << 16);
        *(uint2*)&kvT[((size_t)nh * 64 + 16 * es + ln) * MM + mt * 64 + 16 * w + 4 * quad] = o;
    }
    if (ln == 0) {
        #pragma unroll
        for (int r = 0; r < 4; ++r)
            ksum[(size_t)nh * MM + mt * 64 + 16 * w + 4 * quad + r] = aks[r];
    }
}

__global__ __launch_bounds__(256) void LinearAttention_15985868276494_kv(
        const void* K, const void* V, const void* P, const float* flag,
        const float* cws, unsigned short* kvT, float* ksum) {
    __shared__ unsigned short Ks[64][72];
    __shared__ unsigned short Ps[64][72];
    __shared__ unsigned short VT[64][72];
    __shared__ unsigned short FT[64][72];
    __shared__ float cks[64];
    if (*flag != 0.f) kv_impl<true>(K, V, P, cws, kvT, ksum, Ks, Ps, VT, FT, cks);
    else kv_impl<false>(K, V, P, cws, kvT, ksum, Ks, Ps, VT, FT, cks);
}

// ---------------- out ----------------
template <bool BF16>
__device__ void out_impl(const void* Q, const void* P, const float* cqw,
                         const unsigned short* kvT, const float* ksum, void* out,
                         unsigned short Qs[64][72], unsigned short Ps[64][72],
                         unsigned short KVs[64][72], unsigned short Fs[64][72],
                         unsigned short* kss) {
    const int t = threadIdx.x;
    const int w = t >> 6, ln = t & 15, quad = (t >> 4) & 3;
    const int lb = blockIdx.x, nh = blockIdx.y;
    const int n = nh >> 3, h = nh & 7;
    const size_t qbase = (size_t)n * (LL * ROWSTR) + (size_t)h * 64 + (size_t)(lb * 64) * ROWSTR;

    stage_tile<BF16>(Q, qbase, ROWSTR, Qs, t);
    const float cq = cqw[(size_t)nh * LL + lb * 64 + 16 * w + ln];

    f32x4 ao[4] = {{0.f, 0.f, 0.f, 0.f}, {0.f, 0.f, 0.f, 0.f},
                   {0.f, 0.f, 0.f, 0.f}, {0.f, 0.f, 0.f, 0.f}};
    f32x4 ad = {0.f, 0.f, 0.f, 0.f};

    for (int mt = 0; mt < 32; ++mt) {
        __syncthreads();  // B1: prev MFMA4 reads done (st==0: Qs staged)
        stage_tile<BF16>(P, (size_t)(mt * 64) * 64, 64, Ps, t);
        stage_tile<true>(kvT, (size_t)nh * (64 * MM) + (size_t)(mt * 64), MM, KVs, t);
        if (t < 64) kss[t] = f2bf(ksum[(size_t)nh * MM + mt * 64 + t]);
        __syncthreads();  // B2
        const short8 qb0 = *(const short8*)&Qs[16 * w + ln][quad * 8];
        const short8 qb1 = *(const short8*)&Qs[16 * w + ln][32 + quad * 8];
        #pragma unroll
        for (int ms = 0; ms < 4; ++ms) {
            f32x4 acc = {0.f, 0.f, 0.f, 0.f};
            acc = MFMA(*(const short8*)&Ps[16 * ms + ln][quad * 8], qb0, acc);
            acc = MFMA(*(const short8*)&Ps[16 * ms + ln][32 + quad * 8], qb1, acc);
            float f[4];
            #pragma unroll
            for (int i = 0; i < 4; ++i) {
                const float arg = fminf(fmaf(acc[i], NORMC, -cq), 0.f);
                f[i] = fmaf(__expf(arg), RATIO, REPS);
            }
            uint2 o; o.x = pk2(f[0], f[1]); o.y = pk2(f[2], f[3]);
            *(uint2*)&Fs[16 * w + ln][16 * ms + 4 * quad] = o;
        }
        __syncthreads();  // B3
        #pragma unroll
        for (int k = 0; k < 2; ++k) {
            const short8 af = *(const short8*)&Fs[16 * w + ln][32 * k + quad * 8];
            const short8 bs = *(const short8*)&kss[32 * k + quad * 8];
            ad = MFMA(af, bs, ad);
            #pragma unroll
            for (int es = 0; es < 4; ++es)
                ao[es] = MFMA(af, *(const short8*)&KVs[16 * es + ln][32 * k + quad * 8], ao[es]);
        }
    }
    // epilogue: rows l = lb*64 + 16w + 4quad + reg, cols e = 16es + ln
    float z[4];
    #pragma unroll
    for (int r = 0; r < 4; ++r) z[r] = 1.0f / (ad[r] + EPSD);
    #pragma unroll
    for (int r = 0; r < 4; ++r) {
        const int l = lb * 64 + 16 * w + 4 * quad + r;
        const size_t rowoff = ((size_t)(n * LL + l) * HH + h) * 64;
        #pragma unroll
        for (int es = 0; es < 4; ++es) {
            const float val = ao[es][r] * z[r];
            if (BF16) ((unsigned short*)out)[rowoff + 16 * es + ln] = f2bf(val);
            else ((float*)out)[rowoff + 16 * es + ln] = val;
        }
    }
}

__global__ __launch_bounds__(256) void LinearAttention_15985868276494_out(
        const void* Q, const void* P, const float* flag, const float* cqw,
        const unsigned short* kvT, const float* ksum, void* out) {
    __shared__ unsigned short Qs[64][72];
    __shared__ unsigned short Ps[64][72];
    __shared__ unsigned short KVs[64][72];
    __shared__ unsigned short Fs[64][72];
    __shared__ unsigned short kss[72];
    if (*flag != 0.f) out_impl<true>(Q, P, cqw, kvT, ksum, out, Qs, Ps, KVs, Fs, kss);
    else out_impl<false>(Q, P, cqw, kvT, ksum, out, Qs, Ps, KVs, Fs, kss);
}

extern "C" void kernel_launch(void* const* d_in, const int* in_sizes, int n_in,
                              void* d_out, int out_size, void* d_ws, size_t ws_size,
                              hipStream_t stream) {
    const void* Q = d_in[0];
    const void* K = d_in[1];
    const void* V = d_in[2];
    const void* P = d_in[3];

    float* W = (float*)d_ws;
    float* flag = W;                         // [16]
    float* c_k = W + 16;                     // [16][2048]
    float* c_q = c_k + 16 * 2048;            // [16][2048]
    float* ksumW = c_q + 16 * 2048;          // [16][2048]
    unsigned short* kvTW = (unsigned short*)(ksumW + 16 * 2048);  // [16][64][2048] bf16

    LinearAttention_15985868276494_detect<<<1, 64, 0, stream>>>(
        (const unsigned short*)P, flag);
    LinearAttention_15985868276494_stats<<<512, 256, 0, stream>>>(K, P, flag, c_k);
    LinearAttention_15985868276494_stats<<<512, 256, 0, stream>>>(Q, P, flag, c_q);
    LinearAttention_15985868276494_kv<<<dim3(32, 16), 256, 0, stream>>>(
        K, V, P, flag, c_k, kvTW, ksumW);
    LinearAttention_15985868276494_out<<<dim3(32, 16), 256, 0, stream>>>(
        Q, P, flag, c_q, kvTW, ksumW, d_out);
}